// Round 11
// baseline (386.041 us; speedup 1.0000x reference)
//
#include <hip/hip_runtime.h>
#include <hip/hip_bf16.h>
#include <stdint.h>

typedef float  f32x4 __attribute__((ext_vector_type(4)));
typedef short  s16x8 __attribute__((ext_vector_type(8)));
typedef unsigned short u16x8 __attribute__((ext_vector_type(8)));
typedef unsigned short ushort_t;

__device__ __forceinline__ short f2bf(float f) {
  union { float f; unsigned u; } x; x.f = f;
  unsigned r = x.u + 0x7fffu + ((x.u >> 16) & 1u);
  return (short)(r >> 16);
}
__device__ __forceinline__ float bf2f(unsigned short u) {
  union { unsigned u; float f; } x; x.u = ((unsigned)u) << 16; return x.f;
}

// ---------------- merged weight pack (8 regions) + time embedding (last block)
__device__ __forceinline__ void pack_one(const float* W, int cols, int local, short* dst) {
  int NT = cols / 16;
  int j = local & 7, l = (local >> 3) & 63;
  int nt = (local >> 9) % NT;
  int kt = (local >> 9) / NT;
  int k = kt * 32 + ((l >> 4) * 8) + j;
  int ncol = nt * 16 + (l & 15);
  dst[local] = f2bf(W[(size_t)k * cols + ncol]);
}
__global__ void k_pack_all(const float* __restrict__ w0, const float* __restrict__ w1,
                           const float* __restrict__ w2, const float* __restrict__ w3,
                           const float* __restrict__ w4, const float* __restrict__ w5,
                           const float* __restrict__ w6, const float* __restrict__ w7,
                           short* __restrict__ out,
                           const int* __restrict__ t, const float* __restrict__ tw1,
                           const float* __restrict__ tb1, const float* __restrict__ tw2,
                           const float* __restrict__ tb2, float* __restrict__ temb) {
  if (blockIdx.x == 448) {            // time embedding
    __shared__ float h[32];
    int j = threadIdx.x;
    float tin = (float)t[0] / 1000.0f;
    if (j < 32) h[j] = fmaxf(tin * tw1[j] + tb1[j], 0.f);
    __syncthreads();
    if (j < 32) {
      float acc = tb2[j];
      for (int k = 0; k < 32; ++k) acc += h[k] * tw2[k * 32 + j];
      temb[j] = acc;
    }
    return;
  }
  int i = blockIdx.x * 256 + threadIdx.x;
  if (i >= 114688) return;
  if (i < 98304) {
    int r = i >> 14, local = i & 16383;
    const float* W = r == 0 ? w0 : r == 1 ? w1 : r == 2 ? w2 : r == 3 ? w3 : r == 4 ? w4 : w5;
    pack_one(W, 128, local, out + r * 16384);
  } else {
    int j = i - 98304;
    int r = j >> 13, local = j & 8191;
    pack_one(r ? w7 : w6, 64, local, out + 98304 + r * 8192);
  }
}

// ---------------- x_input = [x_t | cond | t_embed] -> bf16
__global__ void k_build_xin(const float* __restrict__ xt, const float* __restrict__ cond,
                            const float* __restrict__ temb, ushort_t* __restrict__ X, int n) {
  int i = blockIdx.x * 256 + threadIdx.x;   // over n*16, 8 cols each
  if (i >= n * 16) return;
  int node = i >> 4, c8 = i & 15;
  float4 a, b;
  if (c8 < 8)       { const float* p = &xt[(size_t)node * 64 + c8 * 8];
                      a = *(const float4*)p; b = *(const float4*)(p + 4); }
  else if (c8 < 12) { const float* p = &cond[(c8 - 8) * 8];
                      a = *(const float4*)p; b = *(const float4*)(p + 4); }
  else              { const float* p = &temb[(c8 - 12) * 8];
                      a = *(const float4*)p; b = *(const float4*)(p + 4); }
  u16x8 o;
  o[0]=f2bf(a.x); o[1]=f2bf(a.y); o[2]=f2bf(a.z); o[3]=f2bf(a.w);
  o[4]=f2bf(b.x); o[5]=f2bf(b.y); o[6]=f2bf(b.z); o[7]=f2bf(b.w);
  *(u16x8*)&X[(size_t)node * 128 + c8 * 8] = o;
}

// ---------------- CSR build ----------------
__global__ void k_deg_init(int* __restrict__ deg, int n) {
  int i = blockIdx.x * 256 + threadIdx.x;
  if (i < n) deg[i] = 1;
}
__global__ void k_deg_count(const int* __restrict__ edst, int E, int* __restrict__ deg) {
  int e = blockIdx.x * 256 + threadIdx.x;
  if (e < E) atomicAdd(&deg[edst[e]], 1);
}
__global__ void k_scan1(const int* __restrict__ deg, int* __restrict__ tmp,
                        int* __restrict__ bsum, int n) {
  __shared__ int sh[256];
  int i = blockIdx.x * 256 + threadIdx.x;
  int v = (i < n) ? deg[i] : 0;
  sh[threadIdx.x] = v; __syncthreads();
  for (int off = 1; off < 256; off <<= 1) {
    int t = (threadIdx.x >= off) ? sh[threadIdx.x - off] : 0;
    __syncthreads();
    sh[threadIdx.x] += t;
    __syncthreads();
  }
  if (i < n) tmp[i] = sh[threadIdx.x];
  if (threadIdx.x == 255) bsum[blockIdx.x] = sh[255];
}
__global__ void k_scan2(int* __restrict__ bsum, int nb) {
  __shared__ int sh[256];
  int t = threadIdx.x;
  int v = (t < nb) ? bsum[t] : 0;
  sh[t] = v; __syncthreads();
  for (int off = 1; off < 256; off <<= 1) {
    int u = (t >= off) ? sh[t - off] : 0;
    __syncthreads();
    sh[t] += u;
    __syncthreads();
  }
  if (t < nb) bsum[t] = sh[t] - v;
}
__global__ void k_scan3(const int* __restrict__ deg, const int* __restrict__ tmp,
                        const int* __restrict__ bsum, int* __restrict__ row,
                        int* __restrict__ cursor, int n) {
  int i = blockIdx.x * 256 + threadIdx.x;
  if (i < n) {
    int incl = tmp[i] + bsum[i >> 8];
    row[i + 1] = incl;
    cursor[i]  = incl - deg[i];
    if (i == 0) row[0] = 0;
  }
}
// one packed int4 {src, dst, eid, 0} per edge -> single random line per edge
__global__ void k_scatter(const int* __restrict__ ei, int E, int nE,
                          int* __restrict__ cursor, int4* __restrict__ csr4) {
  int e = blockIdx.x * 256 + threadIdx.x;
  if (e >= nE) return;
  int s, d, id;
  if (e < E) { s = ei[e]; d = ei[E + e]; id = e; }
  else       { s = d = e - E; id = -1; }
  int slot = atomicAdd(&cursor[d], 1);
  int4 o; o.x = s; o.y = d; o.z = id; o.w = 0;
  csr4[slot] = o;
}

// ---------------- single node GEMM: out = bf16A[n][128] @ Wp + degf*bias + residb
template<int COLS, bool OUTBF16>
__global__ __launch_bounds__(256)
void k_mgemm(const ushort_t* __restrict__ A, const short* __restrict__ Wp,
             const float* __restrict__ bias, const ushort_t* __restrict__ resid,
             const float* __restrict__ degf, void* __restrict__ out,
             float* __restrict__ out64, int n) {
  const int NT = COLS / 16;
  __shared__ short BL[128 * COLS];
  for (int i = threadIdx.x; i < 128 * COLS / 8; i += 256)
    ((int4*)BL)[i] = ((const int4*)Wp)[i];
  __syncthreads();
  int t = threadIdx.x, wid = t >> 6, lane = t & 63;
  int cg = lane >> 4;
  float bb[NT];
  #pragma unroll
  for (int nt = 0; nt < NT; ++nt)
    bb[nt] = bias ? bias[nt * 16 + (lane & 15)] : 0.f;
  int ntiles = (n + 15) >> 4;
  for (int tile = blockIdx.x * 4 + wid; tile < ntiles; tile += gridDim.x * 4) {
    int r0 = tile << 4;
    int arow = r0 + (lane & 15);
    int crow = arow < n ? arow : 0;
    const ushort_t* Ar = A + (size_t)crow * 128;
    s16x8 Af[4];
    #pragma unroll
    for (int kt = 0; kt < 4; ++kt)
      Af[kt] = *(const s16x8*)(Ar + kt * 32 + cg * 8);
    float dsc[4];
    #pragma unroll
    for (int reg = 0; reg < 4; ++reg) {
      int rr = r0 + cg * 4 + reg;
      dsc[reg] = degf ? degf[rr < n ? rr : 0] : 1.f;
    }
    #pragma unroll
    for (int nt = 0; nt < NT; ++nt) {
      f32x4 acc = {0.f, 0.f, 0.f, 0.f};
      #pragma unroll
      for (int kt = 0; kt < 4; ++kt) {
        s16x8 b = *(const s16x8*)&BL[((kt * NT + nt) * 64 + lane) * 8];
        acc = __builtin_amdgcn_mfma_f32_16x16x32_bf16(Af[kt], b, acc, 0, 0, 0);
      }
      int ncol = nt * 16 + (lane & 15);
      #pragma unroll
      for (int reg = 0; reg < 4; ++reg) {
        int rr = r0 + cg * 4 + reg;
        if (rr < n) {
          float v = acc[reg] + dsc[reg] * bb[nt];
          if (resid) v += bf2f(resid[(size_t)rr * COLS + ncol]);
          if (OUTBF16) ((ushort_t*)out)[(size_t)rr * COLS + ncol] = (ushort_t)f2bf(v);
          else         ((float*)out)[(size_t)rr * COLS + ncol] = v;
          if (out64 && ncol < 64) out64[(size_t)rr * 64 + ncol] = v;
        }
      }
    }
  }
}

// ---------------- dual node GEMM (256 threads): same bf16 A, two packed weights
template<int COLS>
__global__ __launch_bounds__(256)
void k_mgemm_dual(const ushort_t* __restrict__ A, const short* __restrict__ Wp,
                  const float* __restrict__ bias1,
                  ushort_t* __restrict__ out1, ushort_t* __restrict__ out2, int n) {
  const int NT = COLS / 16;
  __shared__ short BL[2 * 128 * COLS];
  for (int i = threadIdx.x; i < 2 * 128 * COLS / 8; i += 256)
    ((int4*)BL)[i] = ((const int4*)Wp)[i];
  __syncthreads();
  int t = threadIdx.x, wid = t >> 6, lane = t & 63;
  int cg = lane >> 4;
  float bb[NT];
  #pragma unroll
  for (int nt = 0; nt < NT; ++nt)
    bb[nt] = bias1 ? bias1[nt * 16 + (lane & 15)] : 0.f;
  int ntiles = (n + 15) >> 4;
  for (int tile = blockIdx.x * 4 + wid; tile < ntiles; tile += gridDim.x * 4) {
    int r0 = tile << 4;
    int arow = r0 + (lane & 15);
    int crow = arow < n ? arow : 0;
    const ushort_t* Ar = A + (size_t)crow * 128;
    s16x8 Af[4];
    #pragma unroll
    for (int kt = 0; kt < 4; ++kt)
      Af[kt] = *(const s16x8*)(Ar + kt * 32 + cg * 8);
    #pragma unroll
    for (int w = 0; w < 2; ++w) {
      ushort_t* outp = w ? out2 : out1;
      #pragma unroll
      for (int nt = 0; nt < NT; ++nt) {
        f32x4 acc = {0.f, 0.f, 0.f, 0.f};
        #pragma unroll
        for (int kt = 0; kt < 4; ++kt) {
          s16x8 b = *(const s16x8*)&BL[(w * 128 * COLS / 8 + (kt * NT + nt) * 64 + lane) * 8];
          acc = __builtin_amdgcn_mfma_f32_16x16x32_bf16(Af[kt], b, acc, 0, 0, 0);
        }
        int ncol = nt * 16 + (lane & 15);
        float badd = w ? 0.f : bb[nt];
        #pragma unroll
        for (int reg = 0; reg < 4; ++reg) {
          int rr = r0 + cg * 4 + reg;
          if (rr < n)
            outp[(size_t)rr * COLS + ncol] = (ushort_t)f2bf(acc[reg] + badd);
        }
      }
    }
  }
}

// ---------------- per-edge aux, layer 1: dist + coord-MLP * edge_vec
__global__ __launch_bounds__(256)
void k_aux1(const int4* __restrict__ csr4, int nE,
            const float* __restrict__ pos,
            const float* __restrict__ cw1, const float* __restrict__ cb1,
            const float* __restrict__ cw2, const float* __restrict__ cb2,
            float4* __restrict__ aux) {
  int k = blockIdx.x * 256 + threadIdx.x;
  if (k >= nE) return;
  int4 c = csr4[k];
  int s = c.x, d = c.y;
  float dx = pos[s*3+0] - pos[d*3+0];
  float dy = pos[s*3+1] - pos[d*3+1];
  float dz = pos[s*3+2] - pos[d*3+2];
  float dist = sqrtf(dx*dx + dy*dy + dz*dz + 1e-8f);
  float h = cb2[0];
  #pragma unroll 4
  for (int j = 0; j < 128; ++j)
    h += fmaxf(fmaf(dist, cw1[j], cb1[j]), 0.f) * cw2[j];
  float4 o; o.x = dist; o.y = h * dx; o.z = h * dy; o.w = h * dz;
  aux[k] = o;
}

// ---------------- per-edge aux, layer 2: dist only
__global__ __launch_bounds__(256)
void k_aux2(const int4* __restrict__ csr4, int nE,
            const float* __restrict__ pos, float* __restrict__ auxd) {
  int k = blockIdx.x * 256 + threadIdx.x;
  if (k >= nE) return;
  int4 c = csr4[k];
  int s = c.x, d = c.y;
  float dx = pos[s*3+0] - pos[d*3+0];
  float dy = pos[s*3+1] - pos[d*3+1];
  float dz = pos[s*3+2] - pos[d*3+2];
  auxd[k] = sqrtf(dx*dx + dy*dy + dz*dz + 1e-8f);
}

// ---------------- per-dst aggregation: one wave per node, TWO 32-lane half-streams.
template<bool L1>
__global__ __launch_bounds__(256)
void k_aggregate(const int* __restrict__ row, const int4* __restrict__ csr4,
                 const float4* __restrict__ aux4, const float* __restrict__ auxd,
                 const ushort_t* __restrict__ Pb, const ushort_t* __restrict__ Qb,
                 const float* __restrict__ w1r,
                 const float* __restrict__ posin, float* __restrict__ posout,
                 float* __restrict__ degf, ushort_t* __restrict__ Sb, int n) {
  int gw = (blockIdx.x * 256 + threadIdx.x) >> 6;
  if (gw >= n) return;
  int lane = threadIdx.x & 63;
  int half = lane >> 5, sub = lane & 31;
  int r0 = row[gw], r1 = row[gw + 1];
  int r1m1 = r1 - 1;                       // deg >= 1 (self loop)

  ushort4 pu = *(const ushort4*)&Pb[(size_t)gw * 128 + (sub << 2)];
  float p0 = bf2f(pu.x), p1 = bf2f(pu.y), p2 = bf2f(pu.z), p3 = bf2f(pu.w);
  float4 wv = *(const float4*)&w1r[sub << 2];
  float a0 = 0.f, a1 = 0.f, a2 = 0.f, a3 = 0.f, pacc = 0.f;

  int k0 = r0 + half;
  bool any = k0 < r1;
  int kA = k0 < r1m1 ? k0 : r1m1;
  int kB = k0 + 2 < r1m1 ? k0 + 2 : r1m1;
  int sA = csr4[kA].x;
  int sB = csr4[kB].x;
  ushort4 qA = *(const ushort4*)&Qb[(size_t)sA * 128 + (sub << 2)];
  float4 axA, axB;
  if (L1) axA = aux4[kA]; else { axA.x = auxd[kA]; axA.y = axA.z = axA.w = 0.f; }

  for (int k = k0; k + 2 < r1; k += 2) {
    int kn4 = k + 4 < r1m1 ? k + 4 : r1m1;
    int sC = csr4[kn4].x;
    ushort4 qB = *(const ushort4*)&Qb[(size_t)sB * 128 + (sub << 2)];
    if (L1) axB = aux4[k + 2]; else { axB.x = auxd[k + 2]; axB.y = axB.z = axB.w = 0.f; }
    a0 += fmaxf(fmaf(axA.x, wv.x, p0 + bf2f(qA.x)), 0.f);
    a1 += fmaxf(fmaf(axA.x, wv.y, p1 + bf2f(qA.y)), 0.f);
    a2 += fmaxf(fmaf(axA.x, wv.z, p2 + bf2f(qA.z)), 0.f);
    a3 += fmaxf(fmaf(axA.x, wv.w, p3 + bf2f(qA.w)), 0.f);
    if (L1 && sub < 3) pacc += (sub == 0) ? axA.y : (sub == 1) ? axA.z : axA.w;
    qA = qB; axA = axB; sB = sC;
  }
  if (any) {
    a0 += fmaxf(fmaf(axA.x, wv.x, p0 + bf2f(qA.x)), 0.f);
    a1 += fmaxf(fmaf(axA.x, wv.y, p1 + bf2f(qA.y)), 0.f);
    a2 += fmaxf(fmaf(axA.x, wv.z, p2 + bf2f(qA.z)), 0.f);
    a3 += fmaxf(fmaf(axA.x, wv.w, p3 + bf2f(qA.w)), 0.f);
    if (L1 && sub < 3) pacc += (sub == 0) ? axA.y : (sub == 1) ? axA.z : axA.w;
  }

  // merge the two halves
  a0 += __shfl_xor(a0, 32, 64);
  a1 += __shfl_xor(a1, 32, 64);
  a2 += __shfl_xor(a2, 32, 64);
  a3 += __shfl_xor(a3, 32, 64);
  if (L1) pacc += __shfl_xor(pacc, 32, 64);

  if (half == 0) {
    ushort4 o;
    o.x = (ushort_t)f2bf(a0); o.y = (ushort_t)f2bf(a1);
    o.z = (ushort_t)f2bf(a2); o.w = (ushort_t)f2bf(a3);
    *(ushort4*)&Sb[(size_t)gw * 128 + (sub << 2)] = o;
  }
  if (L1) {
    if (lane < 3) posout[gw * 3 + lane] = posin[gw * 3 + lane] + pacc;
    if (lane == 0) degf[gw] = (float)(r1 - r0);
  }
}

// ---------------- bond predictor in CSR(dst) order: V[d] L2-hot, write out[eid]
__global__ __launch_bounds__(256)
void k_bond(const int4* __restrict__ csr4, int nE,
            const ushort_t* __restrict__ U, const ushort_t* __restrict__ V,
            const float* __restrict__ w2, const float* __restrict__ b2,
            float* __restrict__ out) {
  __shared__ float w2L[256];
  w2L[threadIdx.x] = w2[threadIdx.x];
  __syncthreads();
  int k = blockIdx.x * 256 + threadIdx.x;
  if (k >= nE) return;
  int4 c = csr4[k];
  int eid = c.z;
  if (eid < 0) return;                   // self loop, no bond output
  int s = c.x, d = c.y;
  const ushort_t* Ur = U + (size_t)s * 64;
  const ushort_t* Vr = V + (size_t)d * 64;
  float l0 = b2[0], l1 = b2[1], l2 = b2[2], l3 = b2[3];
  #pragma unroll
  for (int c8 = 0; c8 < 8; ++c8) {
    u16x8 u = *(const u16x8*)(Ur + c8 * 8);
    u16x8 v = *(const u16x8*)(Vr + c8 * 8);
    #pragma unroll
    for (int j = 0; j < 8; ++j) {
      float h = fmaxf(bf2f(u[j]) + bf2f(v[j]), 0.f);
      const float* wr = &w2L[(c8 * 8 + j) * 4];
      l0 = fmaf(h, wr[0], l0);
      l1 = fmaf(h, wr[1], l1);
      l2 = fmaf(h, wr[2], l2);
      l3 = fmaf(h, wr[3], l3);
    }
  }
  float4 o = {l0, l1, l2, l3};
  *(float4*)&out[(size_t)eid * 4] = o;
}

extern "C" void kernel_launch(void* const* d_in, const int* in_sizes, int n_in,
                              void* d_out, int out_size, void* d_ws, size_t ws_size,
                              hipStream_t stream) {
  const float* x_t   = (const float*)d_in[0];
  const float* pos   = (const float*)d_in[1];
  const int*   ei    = (const int*)d_in[2];
  const int*   tt    = (const int*)d_in[3];
  const float* cond  = (const float*)d_in[4];
  const float* te_w1 = (const float*)d_in[5];
  const float* te_b1 = (const float*)d_in[6];
  const float* te_w2 = (const float*)d_in[7];
  const float* te_b2 = (const float*)d_in[8];
  const float* l1_nm_w1 = (const float*)d_in[9];
  const float* l1_nm_b1 = (const float*)d_in[10];
  const float* l1_nm_w2 = (const float*)d_in[11];
  const float* l1_nm_b2 = (const float*)d_in[12];
  const float* l1_cm_w1 = (const float*)d_in[13];
  const float* l1_cm_b1 = (const float*)d_in[14];
  const float* l1_cm_w2 = (const float*)d_in[15];
  const float* l1_cm_b2 = (const float*)d_in[16];
  const float* l2_nm_w1 = (const float*)d_in[17];
  const float* l2_nm_b1 = (const float*)d_in[18];
  const float* l2_nm_w2 = (const float*)d_in[19];
  const float* l2_nm_b2 = (const float*)d_in[20];
  const float* bp_w1 = (const float*)d_in[25];
  const float* bp_b1 = (const float*)d_in[26];
  const float* bp_w2 = (const float*)d_in[27];
  const float* bp_b2 = (const float*)d_in[28];

  int n  = in_sizes[0] / 64;
  int E_ = in_sizes[2] / 2;
  int nE = E_ + n;
  int nb = (n + 255) / 256;

  uintptr_t base = (uintptr_t)d_ws;
  size_t off = 0;
  auto alloc = [&](size_t bytes) -> void* {
    void* p = (void*)(base + off);
    off += (bytes + 255) & ~(size_t)255;
    return p;
  };
  float* t_emb = (float*)alloc(32 * 4);
  short* pk    = (short*)alloc(114688 * 2);
  short* pk_l1_t = pk;                  // +pk_l1_m adjacent (dual)
  short* pk_l1_2 = pk + 32768;
  short* pk_l2_t = pk + 49152;          // +pk_l2_m adjacent (dual)
  short* pk_l2_2 = pk + 81920;
  short* pk_bp_t = pk + 98304;          // +pk_bp_b adjacent (dual)
  ushort_t* X0b = (ushort_t*)alloc((size_t)n * 128 * 2);
  ushort_t* X1b = (ushort_t*)alloc((size_t)n * 128 * 2);
  ushort_t* Sb  = (ushort_t*)alloc((size_t)n * 128 * 2);
  ushort_t* Pbf = (ushort_t*)alloc((size_t)n * 128 * 2);
  ushort_t* Qbf = (ushort_t*)alloc((size_t)n * 128 * 2);
  int*   deg    = (int*)alloc((size_t)n * 4);
  int*   tmp    = (int*)alloc((size_t)n * 4);
  int*   bsum   = (int*)alloc(256 * 4);
  int*   rowp   = (int*)alloc(((size_t)n + 1) * 4);
  int*   cursor = (int*)alloc((size_t)n * 4);
  int4*  csr4   = (int4*)alloc((size_t)nE * 16);
  float4* aux4  = (float4*)alloc((size_t)nE * 16);
  float* auxd   = (float*)alloc((size_t)nE * 4);
  float* degf   = (float*)alloc((size_t)n * 4);
  float* pos1   = (float*)alloc((size_t)n * 3 * 4);
  ushort_t* Ubf = Pbf;           // reuse after layer-2 aggregate
  ushort_t* Vbf = Qbf;

  // packs + time embed (fused) / input assembly
  k_pack_all<<<449, 256, 0, stream>>>(l1_nm_w1, l1_nm_w1 + 16384, l1_nm_w2,
                                      l2_nm_w1, l2_nm_w1 + 16384, l2_nm_w2,
                                      bp_w1, bp_w1 + 128 * 64, pk,
                                      tt, te_w1, te_b1, te_w2, te_b2, t_emb);
  k_build_xin<<<(n * 16 + 255) / 256, 256, 0, stream>>>(x_t, cond, t_emb, X0b, n);

  // CSR by dst (shared by both layers)
  k_deg_init<<<nb, 256, 0, stream>>>(deg, n);
  k_deg_count<<<(E_ + 255) / 256, 256, 0, stream>>>(ei + E_, E_, deg);
  k_scan1<<<nb, 256, 0, stream>>>(deg, tmp, bsum, n);
  k_scan2<<<1, 256, 0, stream>>>(bsum, nb);
  k_scan3<<<nb, 256, 0, stream>>>(deg, tmp, bsum, rowp, cursor, n);
  k_scatter<<<(nE + 255) / 256, 256, 0, stream>>>(ei, E_, nE, cursor, csr4);

  int nagg = (n + 3) / 4;
  int naux = (nE + 255) / 256;
  int ngemm = (((n + 15) >> 4) + 3) / 4;     // 1 tile per wave exactly

  // ---- layer 1
  k_aux1<<<naux, 256, 0, stream>>>(csr4, nE, pos,
                                   l1_cm_w1, l1_cm_b1, l1_cm_w2, l1_cm_b2, aux4);
  k_mgemm_dual<128><<<ngemm, 256, 0, stream>>>(X0b, pk_l1_t, l1_nm_b1, Pbf, Qbf, n);
  k_aggregate<true><<<nagg, 256, 0, stream>>>(rowp, csr4, aux4, nullptr, Pbf, Qbf,
      l1_nm_w1 + 256 * 128, pos, pos1, degf, Sb, n);
  k_mgemm<128,true><<<ngemm, 256, 0, stream>>>(Sb, pk_l1_2, l1_nm_b2, X0b, degf, X1b, nullptr, n);

  // ---- layer 2 (pos2 dead -> no coord path)
  k_aux2<<<naux, 256, 0, stream>>>(csr4, nE, pos1, auxd);
  k_mgemm_dual<128><<<ngemm, 256, 0, stream>>>(X1b, pk_l2_t, l2_nm_b1, Pbf, Qbf, n);
  k_aggregate<false><<<nagg, 256, 0, stream>>>(rowp, csr4, nullptr, auxd, Pbf, Qbf,
      l2_nm_w1 + 256 * 128, nullptr, nullptr, nullptr, Sb, n);
  // final post-GEMM writes X0b (bf16, feeds bond) AND d_out[:, :64] (f32)
  k_mgemm<128,true><<<ngemm, 256, 0, stream>>>(Sb, pk_l2_2, l2_nm_b2, X1b, degf, X0b, (float*)d_out, n);

  // ---- bond predictor (U,V bf16, reuse P/Q buffers), CSR order
  k_mgemm_dual<64><<<ngemm, 256, 0, stream>>>(X0b, pk_bp_t, bp_b1, Ubf, Vbf, n);
  k_bond<<<(nE + 255) / 256, 256, 0, stream>>>(csr4, nE, Ubf, Vbf,
                                               bp_w2, bp_b2, (float*)d_out + (size_t)n * 64);
}

// Round 12
// 366.314 us; speedup vs baseline: 1.0539x; 1.0539x over previous
//
#include <hip/hip_runtime.h>
#include <hip/hip_bf16.h>
#include <stdint.h>

typedef float  f32x4 __attribute__((ext_vector_type(4)));
typedef short  s16x8 __attribute__((ext_vector_type(8)));
typedef unsigned short u16x8 __attribute__((ext_vector_type(8)));
typedef unsigned short ushort_t;

__device__ __forceinline__ short f2bf(float f) {
  union { float f; unsigned u; } x; x.f = f;
  unsigned r = x.u + 0x7fffu + ((x.u >> 16) & 1u);
  return (short)(r >> 16);
}
__device__ __forceinline__ float bf2f(unsigned short u) {
  union { unsigned u; float f; } x; x.u = ((unsigned)u) << 16; return x.f;
}

// ---------------- merged weight pack (8 regions) + time embedding (last block)
__device__ __forceinline__ void pack_one(const float* W, int cols, int local, short* dst) {
  int NT = cols / 16;
  int j = local & 7, l = (local >> 3) & 63;
  int nt = (local >> 9) % NT;
  int kt = (local >> 9) / NT;
  int k = kt * 32 + ((l >> 4) * 8) + j;
  int ncol = nt * 16 + (l & 15);
  dst[local] = f2bf(W[(size_t)k * cols + ncol]);
}
__global__ void k_pack_all(const float* __restrict__ w0, const float* __restrict__ w1,
                           const float* __restrict__ w2, const float* __restrict__ w3,
                           const float* __restrict__ w4, const float* __restrict__ w5,
                           const float* __restrict__ w6, const float* __restrict__ w7,
                           short* __restrict__ out,
                           const int* __restrict__ t, const float* __restrict__ tw1,
                           const float* __restrict__ tb1, const float* __restrict__ tw2,
                           const float* __restrict__ tb2, float* __restrict__ temb) {
  if (blockIdx.x == 448) {            // time embedding
    __shared__ float h[32];
    int j = threadIdx.x;
    float tin = (float)t[0] / 1000.0f;
    if (j < 32) h[j] = fmaxf(tin * tw1[j] + tb1[j], 0.f);
    __syncthreads();
    if (j < 32) {
      float acc = tb2[j];
      for (int k = 0; k < 32; ++k) acc += h[k] * tw2[k * 32 + j];
      temb[j] = acc;
    }
    return;
  }
  int i = blockIdx.x * 256 + threadIdx.x;
  if (i >= 114688) return;
  if (i < 98304) {
    int r = i >> 14, local = i & 16383;
    const float* W = r == 0 ? w0 : r == 1 ? w1 : r == 2 ? w2 : r == 3 ? w3 : r == 4 ? w4 : w5;
    pack_one(W, 128, local, out + r * 16384);
  } else {
    int j = i - 98304;
    int r = j >> 13, local = j & 8191;
    pack_one(r ? w7 : w6, 64, local, out + 98304 + r * 8192);
  }
}

// ---------------- x_input = [x_t | cond | t_embed] -> bf16
__global__ void k_build_xin(const float* __restrict__ xt, const float* __restrict__ cond,
                            const float* __restrict__ temb, ushort_t* __restrict__ X, int n) {
  int i = blockIdx.x * 256 + threadIdx.x;   // over n*16, 8 cols each
  if (i >= n * 16) return;
  int node = i >> 4, c8 = i & 15;
  float4 a, b;
  if (c8 < 8)       { const float* p = &xt[(size_t)node * 64 + c8 * 8];
                      a = *(const float4*)p; b = *(const float4*)(p + 4); }
  else if (c8 < 12) { const float* p = &cond[(c8 - 8) * 8];
                      a = *(const float4*)p; b = *(const float4*)(p + 4); }
  else              { const float* p = &temb[(c8 - 12) * 8];
                      a = *(const float4*)p; b = *(const float4*)(p + 4); }
  u16x8 o;
  o[0]=f2bf(a.x); o[1]=f2bf(a.y); o[2]=f2bf(a.z); o[3]=f2bf(a.w);
  o[4]=f2bf(b.x); o[5]=f2bf(b.y); o[6]=f2bf(b.z); o[7]=f2bf(b.w);
  *(u16x8*)&X[(size_t)node * 128 + c8 * 8] = o;
}

// ---------------- CSR build ----------------
__global__ void k_deg_init(int* __restrict__ deg, int n) {
  int i = blockIdx.x * 256 + threadIdx.x;
  if (i < n) deg[i] = 1;
}
__global__ void k_deg_count(const int* __restrict__ edst, int E, int* __restrict__ deg) {
  int e = blockIdx.x * 256 + threadIdx.x;
  if (e < E) atomicAdd(&deg[edst[e]], 1);
}
__global__ void k_scan1(const int* __restrict__ deg, int* __restrict__ tmp,
                        int* __restrict__ bsum, int n) {
  __shared__ int sh[256];
  int i = blockIdx.x * 256 + threadIdx.x;
  int v = (i < n) ? deg[i] : 0;
  sh[threadIdx.x] = v; __syncthreads();
  for (int off = 1; off < 256; off <<= 1) {
    int t = (threadIdx.x >= off) ? sh[threadIdx.x - off] : 0;
    __syncthreads();
    sh[threadIdx.x] += t;
    __syncthreads();
  }
  if (i < n) tmp[i] = sh[threadIdx.x];
  if (threadIdx.x == 255) bsum[blockIdx.x] = sh[255];
}
__global__ void k_scan2(int* __restrict__ bsum, int nb) {
  __shared__ int sh[256];
  int t = threadIdx.x;
  int v = (t < nb) ? bsum[t] : 0;
  sh[t] = v; __syncthreads();
  for (int off = 1; off < 256; off <<= 1) {
    int u = (t >= off) ? sh[t - off] : 0;
    __syncthreads();
    sh[t] += u;
    __syncthreads();
  }
  if (t < nb) bsum[t] = sh[t] - v;
}
// cursor padded: one counter per 128B line (index i*32)
__global__ void k_scan3(const int* __restrict__ deg, const int* __restrict__ tmp,
                        const int* __restrict__ bsum, int* __restrict__ row,
                        int* __restrict__ cursor, int n) {
  int i = blockIdx.x * 256 + threadIdx.x;
  if (i < n) {
    int incl = tmp[i] + bsum[i >> 8];
    row[i + 1] = incl;
    cursor[(size_t)i * 32] = incl - deg[i];
    if (i == 0) row[0] = 0;
  }
}
// scatter + fused layer-1 aux (dist + coord-MLP): scatter's VALU is idle anyway
__global__ __launch_bounds__(256)
void k_scatter(const int* __restrict__ ei, int E, int nE,
               int* __restrict__ cursor,
               int* __restrict__ csr_src, int* __restrict__ csr_dst,
               int* __restrict__ csr_eid,
               const float* __restrict__ pos,
               const float* __restrict__ cw1, const float* __restrict__ cb1,
               const float* __restrict__ cw2, const float* __restrict__ cb2,
               float4* __restrict__ aux) {
  int e = blockIdx.x * 256 + threadIdx.x;
  if (e >= nE) return;
  int s, d, id;
  if (e < E) { s = ei[e]; d = ei[E + e]; id = e; }
  else       { s = d = e - E; id = -1; }
  int slot = atomicAdd(&cursor[(size_t)d * 32], 1);
  csr_src[slot] = s;
  csr_dst[slot] = d;
  csr_eid[slot] = id;
  // layer-1 aux under the atomic's latency shadow
  float dx = pos[s*3+0] - pos[d*3+0];
  float dy = pos[s*3+1] - pos[d*3+1];
  float dz = pos[s*3+2] - pos[d*3+2];
  float dist = sqrtf(dx*dx + dy*dy + dz*dz + 1e-8f);
  float h = cb2[0];
  #pragma unroll 4
  for (int j = 0; j < 128; ++j)
    h += fmaxf(fmaf(dist, cw1[j], cb1[j]), 0.f) * cw2[j];
  float4 o; o.x = dist; o.y = h * dx; o.z = h * dy; o.w = h * dz;
  aux[slot] = o;
}

// ---------------- single node GEMM: out = bf16A[n][128] @ Wp + degf*bias + residb
template<int COLS, bool OUTBF16>
__global__ __launch_bounds__(256)
void k_mgemm(const ushort_t* __restrict__ A, const short* __restrict__ Wp,
             const float* __restrict__ bias, const ushort_t* __restrict__ resid,
             const float* __restrict__ degf, void* __restrict__ out,
             float* __restrict__ out64, int n) {
  const int NT = COLS / 16;
  __shared__ short BL[128 * COLS];
  for (int i = threadIdx.x; i < 128 * COLS / 8; i += 256)
    ((int4*)BL)[i] = ((const int4*)Wp)[i];
  __syncthreads();
  int t = threadIdx.x, wid = t >> 6, lane = t & 63;
  int cg = lane >> 4;
  float bb[NT];
  #pragma unroll
  for (int nt = 0; nt < NT; ++nt)
    bb[nt] = bias ? bias[nt * 16 + (lane & 15)] : 0.f;
  int ntiles = (n + 15) >> 4;
  for (int tile = blockIdx.x * 4 + wid; tile < ntiles; tile += gridDim.x * 4) {
    int r0 = tile << 4;
    int arow = r0 + (lane & 15);
    int crow = arow < n ? arow : 0;
    const ushort_t* Ar = A + (size_t)crow * 128;
    s16x8 Af[4];
    #pragma unroll
    for (int kt = 0; kt < 4; ++kt)
      Af[kt] = *(const s16x8*)(Ar + kt * 32 + cg * 8);
    float dsc[4];
    #pragma unroll
    for (int reg = 0; reg < 4; ++reg) {
      int rr = r0 + cg * 4 + reg;
      dsc[reg] = degf ? degf[rr < n ? rr : 0] : 1.f;
    }
    #pragma unroll
    for (int nt = 0; nt < NT; ++nt) {
      f32x4 acc = {0.f, 0.f, 0.f, 0.f};
      #pragma unroll
      for (int kt = 0; kt < 4; ++kt) {
        s16x8 b = *(const s16x8*)&BL[((kt * NT + nt) * 64 + lane) * 8];
        acc = __builtin_amdgcn_mfma_f32_16x16x32_bf16(Af[kt], b, acc, 0, 0, 0);
      }
      int ncol = nt * 16 + (lane & 15);
      #pragma unroll
      for (int reg = 0; reg < 4; ++reg) {
        int rr = r0 + cg * 4 + reg;
        if (rr < n) {
          float v = acc[reg] + dsc[reg] * bb[nt];
          if (resid) v += bf2f(resid[(size_t)rr * COLS + ncol]);
          if (OUTBF16) ((ushort_t*)out)[(size_t)rr * COLS + ncol] = (ushort_t)f2bf(v);
          else         ((float*)out)[(size_t)rr * COLS + ncol] = v;
          if (out64 && ncol < 64) out64[(size_t)rr * 64 + ncol] = v;
        }
      }
    }
  }
}

// ---------------- dual node GEMM (256 threads): same bf16 A, two packed weights
template<int COLS>
__global__ __launch_bounds__(256)
void k_mgemm_dual(const ushort_t* __restrict__ A, const short* __restrict__ Wp,
                  const float* __restrict__ bias1,
                  ushort_t* __restrict__ out1, ushort_t* __restrict__ out2, int n) {
  const int NT = COLS / 16;
  __shared__ short BL[2 * 128 * COLS];
  for (int i = threadIdx.x; i < 2 * 128 * COLS / 8; i += 256)
    ((int4*)BL)[i] = ((const int4*)Wp)[i];
  __syncthreads();
  int t = threadIdx.x, wid = t >> 6, lane = t & 63;
  int cg = lane >> 4;
  float bb[NT];
  #pragma unroll
  for (int nt = 0; nt < NT; ++nt)
    bb[nt] = bias1 ? bias1[nt * 16 + (lane & 15)] : 0.f;
  int ntiles = (n + 15) >> 4;
  for (int tile = blockIdx.x * 4 + wid; tile < ntiles; tile += gridDim.x * 4) {
    int r0 = tile << 4;
    int arow = r0 + (lane & 15);
    int crow = arow < n ? arow : 0;
    const ushort_t* Ar = A + (size_t)crow * 128;
    s16x8 Af[4];
    #pragma unroll
    for (int kt = 0; kt < 4; ++kt)
      Af[kt] = *(const s16x8*)(Ar + kt * 32 + cg * 8);
    #pragma unroll
    for (int w = 0; w < 2; ++w) {
      ushort_t* outp = w ? out2 : out1;
      #pragma unroll
      for (int nt = 0; nt < NT; ++nt) {
        f32x4 acc = {0.f, 0.f, 0.f, 0.f};
        #pragma unroll
        for (int kt = 0; kt < 4; ++kt) {
          s16x8 b = *(const s16x8*)&BL[(w * 128 * COLS / 8 + (kt * NT + nt) * 64 + lane) * 8];
          acc = __builtin_amdgcn_mfma_f32_16x16x32_bf16(Af[kt], b, acc, 0, 0, 0);
        }
        int ncol = nt * 16 + (lane & 15);
        float badd = w ? 0.f : bb[nt];
        #pragma unroll
        for (int reg = 0; reg < 4; ++reg) {
          int rr = r0 + cg * 4 + reg;
          if (rr < n)
            outp[(size_t)rr * COLS + ncol] = (ushort_t)f2bf(acc[reg] + badd);
        }
      }
    }
  }
}

// ---------------- per-edge aux, layer 2: dist only
__global__ __launch_bounds__(256)
void k_aux2(const int* __restrict__ csr_src, const int* __restrict__ csr_dst, int nE,
            const float* __restrict__ pos, float* __restrict__ auxd) {
  int k = blockIdx.x * 256 + threadIdx.x;
  if (k >= nE) return;
  int s = csr_src[k], d = csr_dst[k];
  float dx = pos[s*3+0] - pos[d*3+0];
  float dy = pos[s*3+1] - pos[d*3+1];
  float dz = pos[s*3+2] - pos[d*3+2];
  auxd[k] = sqrtf(dx*dx + dy*dy + dz*dz + 1e-8f);
}

// ---------------- per-dst aggregation: one wave per node, TWO 32-lane half-streams.
template<bool L1>
__global__ __launch_bounds__(256)
void k_aggregate(const int* __restrict__ row, const int* __restrict__ csr_src,
                 const float4* __restrict__ aux4, const float* __restrict__ auxd,
                 const ushort_t* __restrict__ Pb, const ushort_t* __restrict__ Qb,
                 const float* __restrict__ w1r,
                 const float* __restrict__ posin, float* __restrict__ posout,
                 float* __restrict__ degf, ushort_t* __restrict__ Sb, int n) {
  int gw = (blockIdx.x * 256 + threadIdx.x) >> 6;
  if (gw >= n) return;
  int lane = threadIdx.x & 63;
  int half = lane >> 5, sub = lane & 31;
  int r0 = row[gw], r1 = row[gw + 1];
  int r1m1 = r1 - 1;                       // deg >= 1 (self loop)

  ushort4 pu = *(const ushort4*)&Pb[(size_t)gw * 128 + (sub << 2)];
  float p0 = bf2f(pu.x), p1 = bf2f(pu.y), p2 = bf2f(pu.z), p3 = bf2f(pu.w);
  float4 wv = *(const float4*)&w1r[sub << 2];
  float a0 = 0.f, a1 = 0.f, a2 = 0.f, a3 = 0.f, pacc = 0.f;

  int k0 = r0 + half;
  bool any = k0 < r1;
  int kA = k0 < r1m1 ? k0 : r1m1;
  int kB = k0 + 2 < r1m1 ? k0 + 2 : r1m1;
  int sA = csr_src[kA];
  int sB = csr_src[kB];
  ushort4 qA = *(const ushort4*)&Qb[(size_t)sA * 128 + (sub << 2)];
  float4 axA, axB;
  if (L1) axA = aux4[kA]; else { axA.x = auxd[kA]; axA.y = axA.z = axA.w = 0.f; }

  for (int k = k0; k + 2 < r1; k += 2) {
    int kn4 = k + 4 < r1m1 ? k + 4 : r1m1;
    int sC = csr_src[kn4];
    ushort4 qB = *(const ushort4*)&Qb[(size_t)sB * 128 + (sub << 2)];
    if (L1) axB = aux4[k + 2]; else { axB.x = auxd[k + 2]; axB.y = axB.z = axB.w = 0.f; }
    a0 += fmaxf(fmaf(axA.x, wv.x, p0 + bf2f(qA.x)), 0.f);
    a1 += fmaxf(fmaf(axA.x, wv.y, p1 + bf2f(qA.y)), 0.f);
    a2 += fmaxf(fmaf(axA.x, wv.z, p2 + bf2f(qA.z)), 0.f);
    a3 += fmaxf(fmaf(axA.x, wv.w, p3 + bf2f(qA.w)), 0.f);
    if (L1 && sub < 3) pacc += (sub == 0) ? axA.y : (sub == 1) ? axA.z : axA.w;
    qA = qB; axA = axB; sB = sC;
  }
  if (any) {
    a0 += fmaxf(fmaf(axA.x, wv.x, p0 + bf2f(qA.x)), 0.f);
    a1 += fmaxf(fmaf(axA.x, wv.y, p1 + bf2f(qA.y)), 0.f);
    a2 += fmaxf(fmaf(axA.x, wv.z, p2 + bf2f(qA.z)), 0.f);
    a3 += fmaxf(fmaf(axA.x, wv.w, p3 + bf2f(qA.w)), 0.f);
    if (L1 && sub < 3) pacc += (sub == 0) ? axA.y : (sub == 1) ? axA.z : axA.w;
  }

  // merge the two halves
  a0 += __shfl_xor(a0, 32, 64);
  a1 += __shfl_xor(a1, 32, 64);
  a2 += __shfl_xor(a2, 32, 64);
  a3 += __shfl_xor(a3, 32, 64);
  if (L1) pacc += __shfl_xor(pacc, 32, 64);

  if (half == 0) {
    ushort4 o;
    o.x = (ushort_t)f2bf(a0); o.y = (ushort_t)f2bf(a1);
    o.z = (ushort_t)f2bf(a2); o.w = (ushort_t)f2bf(a3);
    *(ushort4*)&Sb[(size_t)gw * 128 + (sub << 2)] = o;
  }
  if (L1) {
    if (lane < 3) posout[gw * 3 + lane] = posin[gw * 3 + lane] + pacc;
    if (lane == 0) degf[gw] = (float)(r1 - r0);
  }
}

// ---------------- bond predictor in CSR(dst) order: V[d] L2-hot, write out[eid]
__global__ __launch_bounds__(256)
void k_bond(const int* __restrict__ csr_src, const int* __restrict__ csr_dst,
            const int* __restrict__ csr_eid, int nE,
            const ushort_t* __restrict__ U, const ushort_t* __restrict__ V,
            const float* __restrict__ w2, const float* __restrict__ b2,
            float* __restrict__ out) {
  __shared__ float w2L[256];
  w2L[threadIdx.x] = w2[threadIdx.x];
  __syncthreads();
  int k = blockIdx.x * 256 + threadIdx.x;
  if (k >= nE) return;
  int eid = csr_eid[k];
  if (eid < 0) return;                   // self loop, no bond output
  int s = csr_src[k], d = csr_dst[k];
  const ushort_t* Ur = U + (size_t)s * 64;
  const ushort_t* Vr = V + (size_t)d * 64;
  float l0 = b2[0], l1 = b2[1], l2 = b2[2], l3 = b2[3];
  #pragma unroll
  for (int c8 = 0; c8 < 8; ++c8) {
    u16x8 u = *(const u16x8*)(Ur + c8 * 8);
    u16x8 v = *(const u16x8*)(Vr + c8 * 8);
    #pragma unroll
    for (int j = 0; j < 8; ++j) {
      float h = fmaxf(bf2f(u[j]) + bf2f(v[j]), 0.f);
      const float* wr = &w2L[(c8 * 8 + j) * 4];
      l0 = fmaf(h, wr[0], l0);
      l1 = fmaf(h, wr[1], l1);
      l2 = fmaf(h, wr[2], l2);
      l3 = fmaf(h, wr[3], l3);
    }
  }
  float4 o = {l0, l1, l2, l3};
  *(float4*)&out[(size_t)eid * 4] = o;
}

extern "C" void kernel_launch(void* const* d_in, const int* in_sizes, int n_in,
                              void* d_out, int out_size, void* d_ws, size_t ws_size,
                              hipStream_t stream) {
  const float* x_t   = (const float*)d_in[0];
  const float* pos   = (const float*)d_in[1];
  const int*   ei    = (const int*)d_in[2];
  const int*   tt    = (const int*)d_in[3];
  const float* cond  = (const float*)d_in[4];
  const float* te_w1 = (const float*)d_in[5];
  const float* te_b1 = (const float*)d_in[6];
  const float* te_w2 = (const float*)d_in[7];
  const float* te_b2 = (const float*)d_in[8];
  const float* l1_nm_w1 = (const float*)d_in[9];
  const float* l1_nm_b1 = (const float*)d_in[10];
  const float* l1_nm_w2 = (const float*)d_in[11];
  const float* l1_nm_b2 = (const float*)d_in[12];
  const float* l1_cm_w1 = (const float*)d_in[13];
  const float* l1_cm_b1 = (const float*)d_in[14];
  const float* l1_cm_w2 = (const float*)d_in[15];
  const float* l1_cm_b2 = (const float*)d_in[16];
  const float* l2_nm_w1 = (const float*)d_in[17];
  const float* l2_nm_b1 = (const float*)d_in[18];
  const float* l2_nm_w2 = (const float*)d_in[19];
  const float* l2_nm_b2 = (const float*)d_in[20];
  const float* bp_w1 = (const float*)d_in[25];
  const float* bp_b1 = (const float*)d_in[26];
  const float* bp_w2 = (const float*)d_in[27];
  const float* bp_b2 = (const float*)d_in[28];

  int n  = in_sizes[0] / 64;
  int E_ = in_sizes[2] / 2;
  int nE = E_ + n;
  int nb = (n + 255) / 256;

  uintptr_t base = (uintptr_t)d_ws;
  size_t off = 0;
  auto alloc = [&](size_t bytes) -> void* {
    void* p = (void*)(base + off);
    off += (bytes + 255) & ~(size_t)255;
    return p;
  };
  float* t_emb = (float*)alloc(32 * 4);
  short* pk    = (short*)alloc(114688 * 2);
  short* pk_l1_t = pk;                  // +pk_l1_m adjacent (dual)
  short* pk_l1_2 = pk + 32768;
  short* pk_l2_t = pk + 49152;          // +pk_l2_m adjacent (dual)
  short* pk_l2_2 = pk + 81920;
  short* pk_bp_t = pk + 98304;          // +pk_bp_b adjacent (dual)
  ushort_t* X0b = (ushort_t*)alloc((size_t)n * 128 * 2);
  ushort_t* X1b = (ushort_t*)alloc((size_t)n * 128 * 2);
  ushort_t* Sb  = (ushort_t*)alloc((size_t)n * 128 * 2);
  ushort_t* Pbf = (ushort_t*)alloc((size_t)n * 128 * 2);
  ushort_t* Qbf = (ushort_t*)alloc((size_t)n * 128 * 2);
  int*   deg    = (int*)alloc((size_t)n * 4);
  int*   tmp    = (int*)alloc((size_t)n * 4);
  int*   bsum   = (int*)alloc(256 * 4);
  int*   rowp   = (int*)alloc(((size_t)n + 1) * 4);
  int*   cursor = (int*)alloc((size_t)n * 128);     // padded: 1 counter / 128B line
  int*   csrsrc = (int*)alloc((size_t)nE * 4);
  int*   csrdst = (int*)alloc((size_t)nE * 4);
  int*   csreid = (int*)alloc((size_t)nE * 4);
  float4* aux4  = (float4*)alloc((size_t)nE * 16);
  float* auxd   = (float*)alloc((size_t)nE * 4);
  float* degf   = (float*)alloc((size_t)n * 4);
  float* pos1   = (float*)alloc((size_t)n * 3 * 4);
  ushort_t* Ubf = Pbf;           // reuse after layer-2 aggregate
  ushort_t* Vbf = Qbf;

  // packs + time embed (fused) / input assembly
  k_pack_all<<<449, 256, 0, stream>>>(l1_nm_w1, l1_nm_w1 + 16384, l1_nm_w2,
                                      l2_nm_w1, l2_nm_w1 + 16384, l2_nm_w2,
                                      bp_w1, bp_w1 + 128 * 64, pk,
                                      tt, te_w1, te_b1, te_w2, te_b2, t_emb);
  k_build_xin<<<(n * 16 + 255) / 256, 256, 0, stream>>>(x_t, cond, t_emb, X0b, n);

  // CSR by dst (shared by both layers); scatter also computes layer-1 aux
  k_deg_init<<<nb, 256, 0, stream>>>(deg, n);
  k_deg_count<<<(E_ + 255) / 256, 256, 0, stream>>>(ei + E_, E_, deg);
  k_scan1<<<nb, 256, 0, stream>>>(deg, tmp, bsum, n);
  k_scan2<<<1, 256, 0, stream>>>(bsum, nb);
  k_scan3<<<nb, 256, 0, stream>>>(deg, tmp, bsum, rowp, cursor, n);
  k_scatter<<<(nE + 255) / 256, 256, 0, stream>>>(ei, E_, nE, cursor,
      csrsrc, csrdst, csreid, pos, l1_cm_w1, l1_cm_b1, l1_cm_w2, l1_cm_b2, aux4);

  int nagg = (n + 3) / 4;
  int naux = (nE + 255) / 256;
  int ngemm = (((n + 15) >> 4) + 3) / 4;     // 1 tile per wave exactly

  // ---- layer 1
  k_mgemm_dual<128><<<ngemm, 256, 0, stream>>>(X0b, pk_l1_t, l1_nm_b1, Pbf, Qbf, n);
  k_aggregate<true><<<nagg, 256, 0, stream>>>(rowp, csrsrc, aux4, nullptr, Pbf, Qbf,
      l1_nm_w1 + 256 * 128, pos, pos1, degf, Sb, n);
  k_mgemm<128,true><<<ngemm, 256, 0, stream>>>(Sb, pk_l1_2, l1_nm_b2, X0b, degf, X1b, nullptr, n);

  // ---- layer 2 (pos2 dead -> no coord path)
  k_aux2<<<naux, 256, 0, stream>>>(csrsrc, csrdst, nE, pos1, auxd);
  k_mgemm_dual<128><<<ngemm, 256, 0, stream>>>(X1b, pk_l2_t, l2_nm_b1, Pbf, Qbf, n);
  k_aggregate<false><<<nagg, 256, 0, stream>>>(rowp, csrsrc, nullptr, auxd, Pbf, Qbf,
      l2_nm_w1 + 256 * 128, nullptr, nullptr, nullptr, Sb, n);
  // final post-GEMM writes X0b (bf16, feeds bond) AND d_out[:, :64] (f32)
  k_mgemm<128,true><<<ngemm, 256, 0, stream>>>(Sb, pk_l2_2, l2_nm_b2, X1b, degf, X0b, (float*)d_out, n);

  // ---- bond predictor (U,V bf16, reuse P/Q buffers), CSR order
  k_mgemm_dual<64><<<ngemm, 256, 0, stream>>>(X0b, pk_bp_t, bp_b1, Ubf, Vbf, n);
  k_bond<<<(nE + 255) / 256, 256, 0, stream>>>(csrsrc, csrdst, csreid, nE, Ubf, Vbf,
                                               bp_w2, bp_b2, (float*)d_out + (size_t)n * 64);
}